// Round 3
// baseline (365.362 us; speedup 1.0000x reference)
//
#include <hip/hip_runtime.h>

typedef __bf16 bf16;
typedef __bf16 bf16x4 __attribute__((ext_vector_type(4)));
typedef __bf16 bf16x8 __attribute__((ext_vector_type(8)));
typedef float f32x4 __attribute__((ext_vector_type(4)));

#define MFMA16(a, b, c) __builtin_amdgcn_mfma_f32_16x16x32_bf16((a), (b), (c), 0, 0, 0)

// Q pre-scale: 1/sqrt(64) * log2(e), so attention uses exp2 directly.
#define QSCALE 0.1803368808f

__device__ __forceinline__ void async_cp16(const bf16* g, bf16* l) {
    __builtin_amdgcn_global_load_lds((const __attribute__((address_space(1))) void*)g,
                                     (__attribute__((address_space(3))) void*)l, 16, 0, 0);
}

// ---------------- fused fp32 -> bf16 conversion (one launch, 7 tensors) ----
struct CvtArgs { const float* src[7]; bf16* dst[7]; };
__global__ void cvt_all(CvtArgs a) {
    int bx = blockIdx.x, t, off;
    if (bx < 12288) { t = bx >> 12;            off = bx & 4095; }
    else            { t = 3 + ((bx - 12288) >> 9); off = (bx - 12288) & 511; }
    size_t i = (size_t)off * 256 + threadIdx.x;
    const float4* p = (const float4*)(a.src[t] + i * 8);
    float4 x = p[0], y = p[1];
    bf16x8 o;
    o[0] = (bf16)x.x; o[1] = (bf16)x.y; o[2] = (bf16)x.z; o[3] = (bf16)x.w;
    o[4] = (bf16)y.x; o[5] = (bf16)y.y; o[6] = (bf16)y.z; o[7] = (bf16)y.w;
    *(bf16x8*)(a.dst[t] + i * 8) = o;
}

// ---------------- GEMM: 256x256 tile, 8 waves, multi-phase counted-vmcnt ---
// C[256,256] tile of A[M,K] * W[N,K]^T, K=1024.
// Schedule (T3+T4+T5 on top of r2's T2 swizzle):
//   staging unit = one K-slice of 32: A[256][32] + B[256][32] = 32 KB.
//   5-unit LDS ring (160 KB) -> prefetch depth 3 phases (~3*320cy covers HBM).
//   Phase h: read frags(unit h%5) | stage unit (h+3)%5 | barrier |
//            lgkmcnt(0)+sched_barrier | setprio(1) 32 MFMA setprio(0) |
//            vmcnt(8) counted (never 0 in main loop) | barrier.
//   Per-wave vmcnt ledger: after phase h staged half h+3, outstanding beyond
//   half h+1 = halves h+2,h+3 = 8 loads -> vmcnt(8). Tail: 8,4,0,none.
// Swizzle: row stride 64B = 4 chunks; slot (r,c) holds global chunk c^(r&3);
//   read of chunk q at row r uses slot q^(r&3). Uniform 8 lanes/bank-group.
// modes as before: 0 Q, 1 K, 2 V^T (token permute), 3 fp32 out.
__device__ __forceinline__ void gemm256(
    const bf16* __restrict__ A, const bf16* __restrict__ W,
    const float* __restrict__ bias, void* __restrict__ Cout,
    int mode, int m0, int n0)
{
    __shared__ bf16 lds[81920];   // 5 units x 16384 elem (A:0..8191 | B:8192..16383)
    const int K = 1024;
    const int tid = threadIdx.x;
    const int lane = tid & 63, wave = tid >> 6;
    const int l15 = lane & 15, quad = lane >> 4;
    const int wm = wave >> 2, wn = wave & 3;   // 2 x 4 waves, wave-tile 128x64

    f32x4 acc[8][4] = {};

    // staging: thread covers granules {tid, tid+512} of A and of B per unit.
    // granule g: row g>>2, chunk g&3; src chunk = (g&3)^(row&3). rows of the
    // two granules differ by 128 (== 0 mod 4) so the swizzle term is shared.
    const int rA = tid >> 2;
    const int cg8 = ((tid & 3) ^ (rA & 3)) * 8;
    const bf16* Ag0 = A + (size_t)(m0 + rA) * K + cg8;
    const bf16* Ag1 = A + (size_t)(m0 + rA + 128) * K + cg8;
    const bf16* Bg0 = W + (size_t)(n0 + rA) * K + cg8;
    const bf16* Bg1 = W + (size_t)(n0 + rA + 128) * K + cg8;

    auto stage = [&](int u, int k0) {
        bf16* p = lds + u;
        async_cp16(Ag0 + k0, p + tid * 8);
        async_cp16(Ag1 + k0, p + (tid + 512) * 8);
        async_cp16(Bg0 + k0, p + 8192 + tid * 8);
        async_cp16(Bg1 + k0, p + 8192 + (tid + 512) * 8);
    };

    // frag read offsets within a unit (k-chunk quad, swizzled by row&3=l15&3)
    const int csw = (quad ^ (l15 & 3)) * 8;
    int afo[8], bfo[4];
#pragma unroll
    for (int mt = 0; mt < 8; ++mt) afo[mt] = (wm * 128 + mt * 16 + l15) * 32 + csw;
#pragma unroll
    for (int nt = 0; nt < 4; ++nt) bfo[nt] = 8192 + (wn * 64 + nt * 16 + l15) * 32 + csw;

    // phase: vmsel 2 -> vmcnt(8), 1 -> vmcnt(4), 0 -> vmcnt(0), -1 -> none
    auto phase = [&](int cu, int su, int k0s, bool doStage, int vmsel) {
        bf16x8 af[8], bf[4];
#pragma unroll
        for (int mt = 0; mt < 8; ++mt) af[mt] = *(const bf16x8*)(lds + cu + afo[mt]);
#pragma unroll
        for (int nt = 0; nt < 4; ++nt) bf[nt] = *(const bf16x8*)(lds + cu + bfo[nt]);
        if (doStage) stage(su, k0s);
        __builtin_amdgcn_s_barrier();
        asm volatile("s_waitcnt lgkmcnt(0)" ::: "memory");
        __builtin_amdgcn_sched_barrier(0);    // rule 18: MFMA must not hoist
        __builtin_amdgcn_s_setprio(1);
#pragma unroll
        for (int mt = 0; mt < 8; ++mt)
#pragma unroll
            for (int nt = 0; nt < 4; ++nt)
                acc[mt][nt] = MFMA16(af[mt], bf[nt], acc[mt][nt]);
        __builtin_amdgcn_s_setprio(0);
        if (vmsel == 2)      asm volatile("s_waitcnt vmcnt(8)" ::: "memory");
        else if (vmsel == 1) asm volatile("s_waitcnt vmcnt(4)" ::: "memory");
        else if (vmsel == 0) asm volatile("s_waitcnt vmcnt(0)" ::: "memory");
        if (vmsel >= 0) __builtin_amdgcn_s_barrier();
    };

    // LDS ring (element offsets), rotate left each phase
    int r0 = 0, r1 = 16384, r2 = 32768, r3 = 49152, r4 = 65536;
    auto rot = [&]() { int tmp = r0; r0 = r1; r1 = r2; r2 = r3; r3 = r4; r4 = tmp; };

    // prologue: stage halves 0,1,2; wait half 0 (leave 1,2 in flight)
    stage(r0, 0); stage(r1, 32); stage(r2, 64);
    asm volatile("s_waitcnt vmcnt(8)" ::: "memory");
    __builtin_amdgcn_s_barrier();

    // main: halves 0..27, steady state
    for (int t = 0; t < 14; ++t) {
        phase(r0, r3, (2 * t + 3) * 32, true, 2); rot();
        phase(r0, r3, (2 * t + 4) * 32, true, 2); rot();
    }
    // tail: halves 28..31
    phase(r0, r3, 31 * 32, true, 2); rot();   // h=28, stages last half
    phase(r0, 0, 0, false, 1); rot();         // h=29
    phase(r0, 0, 0, false, 0); rot();         // h=30
    phase(r0, 0, 0, false, -1);               // h=31

    // epilogue
#pragma unroll
    for (int mt = 0; mt < 8; ++mt) {
#pragma unroll
        for (int nt = 0; nt < 4; ++nt) {
            int col = n0 + wn * 64 + nt * 16 + l15;
            float bcol = (mode == 2) ? 0.0f : bias[col];
#pragma unroll
            for (int r = 0; r < 4; ++r) {
                int row = m0 + wm * 128 + mt * 16 + quad * 4 + r;
                float val = acc[mt][nt][r];
                if (mode == 2) {
                    val += bias[row];
                    int bb = col >> 11, s = col & 2047;
                    int u = s & 31;
                    int sp = (s & ~31) | (((u >> 2) & 3) * 8 + (u >> 4) * 4 + (u & 3));
                    ((bf16*)Cout)[((size_t)(bb * 1024 + row) << 11) + sp] = (bf16)val;
                } else if (mode == 3) {
                    ((float*)Cout)[(size_t)row * 1024 + col] = val + bcol;
                } else {
                    val += bcol;
                    if (mode == 0) val *= QSCALE;
                    int bb = row >> 11, s = row & 2047, hh = col >> 6, d = col & 63;
                    ((bf16*)Cout)[(((size_t)(bb * 16 + hh) * 2048 + s) << 6) + d] = (bf16)val;
                }
            }
        }
    }
}

struct QkvArgs {
    const bf16* A[3];
    const bf16* W[3];
    const float* bias[3];
    bf16* out[3];
};

// grid 384 = 3 GEMMs x 128 tiles of 256^2. XCD swizzle (384%8==0): XCD j gets
// 48 contiguous tile ids; n-fastest order -> A-panel reuse within an XCD L2.
__global__ __launch_bounds__(512, 2) void qkv_gemm(QkvArgs t) {
    int bid = blockIdx.x;
    int idx = (bid & 7) * 48 + (bid >> 3);
    int z = idx >> 7, r = idx & 127;
    int m0, n0;
    if (z < 2) { m0 = (r >> 2) * 256; n0 = (r & 3) * 256; }   // M=8192, N=1024
    else       { m0 = (r >> 5) * 256; n0 = (r & 31) * 256; }  // V^T: M=1024, N=8192
    gemm256(t.A[z], t.W[z], t.bias[z], t.out[z], z, m0, n0);
}

// O-projection: fp32 out, 128 tiles
__global__ __launch_bounds__(512, 2) void oproj_gemm(
    const bf16* __restrict__ A, const bf16* __restrict__ W,
    const float* __restrict__ bias, float* __restrict__ Cout) {
    int bid = blockIdx.x;
    int idx = (bid & 7) * 16 + (bid >> 3);
    gemm256(A, W, bias, Cout, 3, (idx >> 2) * 256, (idx & 3) * 256);
}

// ---------------- flash attention: S^T trick, full-rate PV ----------------
// (unchanged from r2)
__global__ __launch_bounds__(256, 2) void attn_kernel(
    const bf16* __restrict__ Qh, const bf16* __restrict__ Kh,
    const bf16* __restrict__ Vtg, bf16* __restrict__ AO)
{
    __shared__ bf16 Kl[64 * 64];   // [key][d], 16B chunk c holds src chunk c^(key&7)
    __shared__ bf16 Vl[64 * 64];   // [d][key'], 16B chunk c holds src chunk c^(d&7)

    const int tid = threadIdx.x;
    const int lane = tid & 63, wave = tid >> 6;
    const int l15 = lane & 15, quad = lane >> 4, l7 = l15 & 7;
    const int h = blockIdx.y, b = blockIdx.z;
    const size_t base = (size_t)(b * 16 + h) << 17;   // * 2048 * 64
    const int q0 = blockIdx.x * 256 + wave * 64;

    // Q fragments (pre-scaled by QSCALE): B operand of S^T
    bf16x8 qf[4][2];
#pragma unroll
    for (int qt = 0; qt < 4; ++qt)
#pragma unroll
        for (int ks = 0; ks < 2; ++ks)
            qf[qt][ks] = *(const bf16x8*)(Qh + base + (q0 + qt * 16 + l15) * 64 + ks * 32 + quad * 8);

    f32x4 o[4][4] = {};   // O^T tiles: [dt][qt], lane l15=q, rows d=quad*4+r
    float ls[4] = {};     // per-q partial row sums (q = l15)

    const int sr = tid >> 3;
    const int sc0 = ((tid & 7) ^ (sr & 7)) * 8;
    const int sr2 = sr + 32;

    for (int kt = 0; kt < 2048; kt += 64) {
        __syncthreads();
        async_cp16(Kh + base + (size_t)(kt + sr) * 64 + sc0, Kl + tid * 8);
        async_cp16(Kh + base + (size_t)(kt + sr2) * 64 + sc0, Kl + (tid + 256) * 8);
        async_cp16(Vtg + base + (size_t)sr * 2048 + kt + sc0, Vl + tid * 8);
        async_cp16(Vtg + base + (size_t)sr2 * 2048 + kt + sc0, Vl + (tid + 256) * 8);
        __syncthreads();

        bf16x8 kb[2][4];
#pragma unroll
        for (int ks = 0; ks < 2; ++ks)
#pragma unroll
            for (int ktile = 0; ktile < 4; ++ktile)
                kb[ks][ktile] = *(const bf16x8*)(Kl + (ktile * 16 + l15) * 64 + (((ks * 4 + quad) ^ l7) * 8));

        bf16x8 pf[4][2];
#pragma unroll
        for (int qt = 0; qt < 4; ++qt) {
            f32x4 sc[4] = {};
#pragma unroll
            for (int ks = 0; ks < 2; ++ks)
#pragma unroll
                for (int ktile = 0; ktile < 4; ++ktile)
                    sc[ktile] = MFMA16(kb[ks][ktile], qf[qt][ks], sc[ktile]);
            float sum = 0.0f;
#pragma unroll
            for (int kc = 0; kc < 2; ++kc) {
                bf16x8 pk;
#pragma unroll
                for (int t = 0; t < 2; ++t)
#pragma unroll
                    for (int r = 0; r < 4; ++r) {
                        float p = __builtin_amdgcn_exp2f(sc[kc * 2 + t][r]);
                        sum += p;
                        pk[t * 4 + r] = (bf16)p;
                    }
                pf[qt][kc] = pk;
            }
            ls[qt] += sum;
        }

        bf16x8 va[4][2];
#pragma unroll
        for (int dt = 0; dt < 4; ++dt)
#pragma unroll
            for (int kc = 0; kc < 2; ++kc)
                va[dt][kc] = *(const bf16x8*)(Vl + (dt * 16 + l15) * 64 + (((kc * 4 + quad) ^ l7) * 8));

#pragma unroll
        for (int dt = 0; dt < 4; ++dt)
#pragma unroll
            for (int qt = 0; qt < 4; ++qt)
#pragma unroll
                for (int kc = 0; kc < 2; ++kc)
                    o[dt][qt] = MFMA16(va[dt][kc], pf[qt][kc], o[dt][qt]);
    }

#pragma unroll
    for (int qt = 0; qt < 4; ++qt) {
        float l = ls[qt];
        l += __shfl_xor(l, 16, 64);
        l += __shfl_xor(l, 32, 64);
        float inv = 1.0f / l;
        size_t rb = ((size_t)(b * 2048 + q0 + qt * 16 + l15)) * 1024 + h * 64;
#pragma unroll
        for (int dt = 0; dt < 4; ++dt) {
            bf16x4 ov = {(bf16)(o[dt][qt][0] * inv), (bf16)(o[dt][qt][1] * inv),
                         (bf16)(o[dt][qt][2] * inv), (bf16)(o[dt][qt][3] * inv)};
            *(bf16x4*)(AO + rb + dt * 16 + quad * 4) = ov;
        }
    }
}

// ---------------- host ----------------
extern "C" void kernel_launch(void* const* d_in, const int* in_sizes, int n_in,
                              void* d_out, int out_size, void* d_ws, size_t ws_size,
                              hipStream_t stream) {
    const float* q  = (const float*)d_in[0];
    const float* k  = (const float*)d_in[1];
    const float* v  = (const float*)d_in[2];
    const float* Wq = (const float*)d_in[3];
    const float* bq = (const float*)d_in[4];
    const float* Wk = (const float*)d_in[5];
    const float* bk = (const float*)d_in[6];
    const float* Wv = (const float*)d_in[7];
    const float* bv = (const float*)d_in[8];
    const float* Wo = (const float*)d_in[9];
    const float* bo = (const float*)d_in[10];
    float* out = (float*)d_out;

    const size_t NX = (size_t)8192 * 1024;
    const size_t NW = (size_t)1024 * 1024;
    bf16* ws  = (bf16*)d_ws;
    bf16* Xq  = ws;            // reused as AO after projections
    bf16* Xk  = Xq + NX;
    bf16* Xv  = Xk + NX;
    bf16* Wqb = Xv + NX;
    bf16* Wkb = Wqb + NW;
    bf16* Wvb = Wkb + NW;
    bf16* Wob = Wvb + NW;
    bf16* Qh  = Wob + NW;      // [B,H,S,D], pre-scaled by QSCALE
    bf16* Kh  = Qh + NX;       // [B,H,S,D]
    bf16* Vt  = Kh + NX;       // [B,H,D,S'] (tokens permuted within 32-groups)
    bf16* AO  = Xq;

    CvtArgs ca;
    ca.src[0] = q;  ca.dst[0] = Xq;
    ca.src[1] = k;  ca.dst[1] = Xk;
    ca.src[2] = v;  ca.dst[2] = Xv;
    ca.src[3] = Wq; ca.dst[3] = Wqb;
    ca.src[4] = Wk; ca.dst[4] = Wkb;
    ca.src[5] = Wv; ca.dst[5] = Wvb;
    ca.src[6] = Wo; ca.dst[6] = Wob;
    cvt_all<<<14336, 256, 0, stream>>>(ca);

    QkvArgs t;
    t.A[0] = Xq;  t.W[0] = Wqb; t.bias[0] = bq; t.out[0] = Qh;
    t.A[1] = Xk;  t.W[1] = Wkb; t.bias[1] = bk; t.out[1] = Kh;
    t.A[2] = Wvb; t.W[2] = Xv;  t.bias[2] = bv; t.out[2] = Vt;   // V^T: A=Wv, W=Xv
    qkv_gemm<<<384, 512, 0, stream>>>(t);

    attn_kernel<<<dim3(8, 16, 4), dim3(256, 1, 1), 0, stream>>>(Qh, Kh, Vt, AO);

    oproj_gemm<<<128, 512, 0, stream>>>(AO, Wob, bo, out);
}

// Round 4
// 354.366 us; speedup vs baseline: 1.0310x; 1.0310x over previous
//
#include <hip/hip_runtime.h>

typedef __bf16 bf16;
typedef __bf16 bf16x4 __attribute__((ext_vector_type(4)));
typedef __bf16 bf16x8 __attribute__((ext_vector_type(8)));
typedef float f32x4 __attribute__((ext_vector_type(4)));

#define MFMA16(a, b, c) __builtin_amdgcn_mfma_f32_16x16x32_bf16((a), (b), (c), 0, 0, 0)

// Q pre-scale: 1/sqrt(64) * log2(e), so attention uses exp2 directly.
#define QSCALE 0.1803368808f

__device__ __forceinline__ void async_cp16(const bf16* g, bf16* l) {
    __builtin_amdgcn_global_load_lds((const __attribute__((address_space(1))) void*)g,
                                     (__attribute__((address_space(3))) void*)l, 16, 0, 0);
}

// ---------------- fused fp32 -> bf16 conversion (one launch, 7 tensors) ----
struct CvtArgs { const float* src[7]; bf16* dst[7]; };
__global__ void cvt_all(CvtArgs a) {
    int bx = blockIdx.x, t, off;
    if (bx < 12288) { t = bx >> 12;            off = bx & 4095; }
    else            { t = 3 + ((bx - 12288) >> 9); off = (bx - 12288) & 511; }
    size_t i = (size_t)off * 256 + threadIdx.x;
    const float4* p = (const float4*)(a.src[t] + i * 8);
    float4 x = p[0], y = p[1];
    bf16x8 o;
    o[0] = (bf16)x.x; o[1] = (bf16)x.y; o[2] = (bf16)x.z; o[3] = (bf16)x.w;
    o[4] = (bf16)y.x; o[5] = (bf16)y.y; o[6] = (bf16)y.z; o[7] = (bf16)y.w;
    *(bf16x8*)(a.dst[t] + i * 8) = o;
}

// ---------------- GEMM: 256x256 tile, 8 waves, counted-vmcnt ring v2 ------
// r3 post-mortem fixes:
//  (a) swizzle: BK=32 row = 64B = 4 chunks; conflict-free needs distinct
//      (4*row + c) mod 8 per 8-lane batch. Store slot (r,s) <- global chunk
//      (s - (r>>1))&3; read logical chunk q at slot (q + (r>>1))&3.
//      Verified: positions 4*(r&1) + (q + (r>>1))&3 distinct for rows 0..7.
//  (b) ring 5 -> 4 units (128 KB). stage slice h+2 at phase h; trailing
//      vmcnt(4) leaves the newest unit in flight (T4: never drain-0 in loop).
// modes: 0 Q, 1 K, 2 V^T (token permute), 3 fp32 out.
__device__ __forceinline__ void gemm256(
    const bf16* __restrict__ A, const bf16* __restrict__ W,
    const float* __restrict__ bias, void* __restrict__ Cout,
    int mode, int m0, int n0)
{
    __shared__ bf16 lds[65536];   // 4 units x 16384 elem (A:0..8191 | B:8192..16383)
    const int K = 1024;
    const int tid = threadIdx.x;
    const int lane = tid & 63, wave = tid >> 6;
    const int l15 = lane & 15, quad = lane >> 4;
    const int wm = wave >> 2, wn = wave & 3;   // 2 x 4 waves, wave-tile 128x64

    f32x4 acc[8][4] = {};

    // staging: thread covers granules {tid, tid+512} of A and of B per unit.
    // slot (r, s=tid&3) gets global chunk (s - (r>>1))&3. Rows rA and rA+128
    // share the swizzle term (128>>1 = 64 == 0 mod 4).
    const int rA = tid >> 2;
    const int cg8 = (((tid & 3) - (rA >> 1)) & 3) * 8;
    const bf16* Ag0 = A + (size_t)(m0 + rA) * K + cg8;
    const bf16* Ag1 = A + (size_t)(m0 + rA + 128) * K + cg8;
    const bf16* Bg0 = W + (size_t)(n0 + rA) * K + cg8;
    const bf16* Bg1 = W + (size_t)(n0 + rA + 128) * K + cg8;

    auto stage = [&](int u, int k0) {
        bf16* p = lds + u;
        async_cp16(Ag0 + k0, p + tid * 8);
        async_cp16(Ag1 + k0, p + (tid + 512) * 8);
        async_cp16(Bg0 + k0, p + 8192 + tid * 8);
        async_cp16(Bg1 + k0, p + 8192 + (tid + 512) * 8);
    };

    // frag read: logical k-chunk = quad, at slot (quad + (row>>1))&3.
    // (row>>1)&3 == (l15>>1)&3 since wm*128, mt*16 are == 0 mod 8.
    const int csw = ((quad + (l15 >> 1)) & 3) * 8;
    int afo[8], bfo[4];
#pragma unroll
    for (int mt = 0; mt < 8; ++mt) afo[mt] = (wm * 128 + mt * 16 + l15) * 32 + csw;
#pragma unroll
    for (int nt = 0; nt < 4; ++nt) bfo[nt] = 8192 + (wn * 64 + nt * 16 + l15) * 32 + csw;

    // vmsel: 1 -> vmcnt(4), 0 -> vmcnt(0), -1 -> none
    auto phase = [&](int cu, int su, int k0s, bool doStage, int vmsel) {
        bf16x8 af[8], bf[4];
#pragma unroll
        for (int mt = 0; mt < 8; ++mt) af[mt] = *(const bf16x8*)(lds + cu + afo[mt]);
#pragma unroll
        for (int nt = 0; nt < 4; ++nt) bf[nt] = *(const bf16x8*)(lds + cu + bfo[nt]);
        if (doStage) stage(su, k0s);
        __builtin_amdgcn_s_barrier();
        asm volatile("s_waitcnt lgkmcnt(0)" ::: "memory");
        __builtin_amdgcn_sched_barrier(0);    // rule 18: MFMA must not hoist
        __builtin_amdgcn_s_setprio(1);
#pragma unroll
        for (int mt = 0; mt < 8; ++mt)
#pragma unroll
            for (int nt = 0; nt < 4; ++nt)
                acc[mt][nt] = MFMA16(af[mt], bf[nt], acc[mt][nt]);
        __builtin_amdgcn_s_setprio(0);
        if (vmsel == 1)      asm volatile("s_waitcnt vmcnt(4)" ::: "memory");
        else if (vmsel == 0) asm volatile("s_waitcnt vmcnt(0)" ::: "memory");
        if (vmsel >= 0) __builtin_amdgcn_s_barrier();
    };

    const int U0 = 0, U1 = 16384, U2 = 32768, U3 = 49152;

    // prologue: stage slices 0,1; wait slice 0 (leave 1 in flight)
    stage(U0, 0); stage(U1, 32);
    asm volatile("s_waitcnt vmcnt(4)" ::: "memory");
    __builtin_amdgcn_s_barrier();

    // phases h=0..27: read slot h%4, stage slice h+2 -> slot (h+2)%4
    for (int t = 0; t < 7; ++t) {
        const int kb = t * 128;
        phase(U0, U2, kb + 64, true, 1);
        phase(U1, U3, kb + 96, true, 1);
        phase(U2, U0, kb + 128, true, 1);
        phase(U3, U1, kb + 160, true, 1);
    }
    phase(U0, U2, 960, true, 1);   // h=28 stages slice 30
    phase(U1, U3, 992, true, 1);   // h=29 stages slice 31
    phase(U2, 0, 0, false, 0);     // h=30: drain, slice 31 landed
    phase(U3, 0, 0, false, -1);    // h=31

    // epilogue
#pragma unroll
    for (int mt = 0; mt < 8; ++mt) {
#pragma unroll
        for (int nt = 0; nt < 4; ++nt) {
            int col = n0 + wn * 64 + nt * 16 + l15;
            float bcol = (mode == 2) ? 0.0f : bias[col];
#pragma unroll
            for (int r = 0; r < 4; ++r) {
                int row = m0 + wm * 128 + mt * 16 + quad * 4 + r;
                float val = acc[mt][nt][r];
                if (mode == 2) {
                    val += bias[row];
                    int bb = col >> 11, s = col & 2047;
                    int u = s & 31;
                    int sp = (s & ~31) | (((u >> 2) & 3) * 8 + (u >> 4) * 4 + (u & 3));
                    ((bf16*)Cout)[((size_t)(bb * 1024 + row) << 11) + sp] = (bf16)val;
                } else if (mode == 3) {
                    ((float*)Cout)[(size_t)row * 1024 + col] = val + bcol;
                } else {
                    val += bcol;
                    if (mode == 0) val *= QSCALE;
                    int bb = row >> 11, s = row & 2047, hh = col >> 6, d = col & 63;
                    ((bf16*)Cout)[(((size_t)(bb * 16 + hh) * 2048 + s) << 6) + d] = (bf16)val;
                }
            }
        }
    }
}

// ---------------- 128x128 GEMM core (r2, proven: 0 conflicts) -------------
// BK=64, single-buffered. Row = 128B = 8 chunks; swizzle c ^ (r&7) is
// conflict-free (verified r2: SQ_LDS_BANK_CONFLICT = 0). Used by oproj.
__device__ __forceinline__ void gemm_core(
    const bf16* __restrict__ A, const bf16* __restrict__ W,
    const float* __restrict__ bias, void* __restrict__ Cout,
    int mode, int m0, int n0)
{
    __shared__ bf16 As[128 * 64];
    __shared__ bf16 Bs[128 * 64];
    const int K = 1024;
    const int tid = threadIdx.x;
    const int lane = tid & 63, wave = tid >> 6;
    const int l15 = lane & 15, quad = lane >> 4, l7 = l15 & 7;
    const int wm = wave >> 1, wn = wave & 1;

    f32x4 acc[4][4] = {};

    const int rb = tid >> 3;
    const int cg8 = ((tid & 7) ^ (rb & 7)) * 8;
    const bf16* Ag = A + (size_t)(m0 + rb) * K + cg8;
    const bf16* Wg = W + (size_t)(n0 + rb) * K + cg8;
    bf16* Al = As + tid * 8;
    bf16* Bl = Bs + tid * 8;

    for (int k0 = 0; k0 < K; k0 += 64) {
        __syncthreads();
#pragma unroll
        for (int j = 0; j < 4; ++j) {
            async_cp16(Ag + k0 + (size_t)(j * 32) * K, Al + j * 2048);
            async_cp16(Wg + k0 + (size_t)(j * 32) * K, Bl + j * 2048);
        }
        __syncthreads();

#pragma unroll
        for (int ks = 0; ks < 2; ++ks) {
            bf16x8 af[4], bfr[4];
#pragma unroll
            for (int t = 0; t < 4; ++t) {
                const int sw = ((ks * 4 + quad) ^ l7) * 8;
                af[t]  = *(const bf16x8*)(As + (wm * 64 + t * 16 + l15) * 64 + sw);
                bfr[t] = *(const bf16x8*)(Bs + (wn * 64 + t * 16 + l15) * 64 + sw);
            }
#pragma unroll
            for (int mt = 0; mt < 4; ++mt)
#pragma unroll
                for (int nt = 0; nt < 4; ++nt)
                    acc[mt][nt] = MFMA16(af[mt], bfr[nt], acc[mt][nt]);
        }
    }

#pragma unroll
    for (int mt = 0; mt < 4; ++mt) {
#pragma unroll
        for (int nt = 0; nt < 4; ++nt) {
            int col = n0 + wn * 64 + nt * 16 + l15;
            float bcol = (mode == 2) ? 0.0f : bias[col];
#pragma unroll
            for (int r = 0; r < 4; ++r) {
                int row = m0 + wm * 64 + mt * 16 + quad * 4 + r;
                float val = acc[mt][nt][r];
                if (mode == 2) {
                    val += bias[row];
                    int bb = col >> 11, s = col & 2047;
                    int u = s & 31;
                    int sp = (s & ~31) | (((u >> 2) & 3) * 8 + (u >> 4) * 4 + (u & 3));
                    ((bf16*)Cout)[((size_t)(bb * 1024 + row) << 11) + sp] = (bf16)val;
                } else if (mode == 3) {
                    ((float*)Cout)[(size_t)row * 1024 + col] = val + bcol;
                } else {
                    val += bcol;
                    if (mode == 0) val *= QSCALE;
                    int bb = row >> 11, s = row & 2047, hh = col >> 6, d = col & 63;
                    ((bf16*)Cout)[(((size_t)(bb * 16 + hh) * 2048 + s) << 6) + d] = (bf16)val;
                }
            }
        }
    }
}

struct QkvArgs {
    const bf16* A[3];
    const bf16* W[3];
    const float* bias[3];
    bf16* out[3];
};

// grid 384 = 3 GEMMs x 128 tiles of 256^2. XCD swizzle (384%8==0).
__global__ __launch_bounds__(512, 2) void qkv_gemm(QkvArgs t) {
    int bid = blockIdx.x;
    int idx = (bid & 7) * 48 + (bid >> 3);
    int z = idx >> 7, r = idx & 127;
    int m0, n0;
    if (z < 2) { m0 = (r >> 2) * 256; n0 = (r & 3) * 256; }   // M=8192, N=1024
    else       { m0 = (r >> 5) * 256; n0 = (r & 31) * 256; }  // V^T: M=1024, N=8192
    gemm256(t.A[z], t.W[z], t.bias[z], t.out[z], z, m0, n0);
}

// O-projection: fp32 out, r2-proven 128^2 core, 512 blocks (2 full rounds)
__global__ __launch_bounds__(256) void oproj_gemm(
    const bf16* __restrict__ A, const bf16* __restrict__ W,
    const float* __restrict__ bias, float* __restrict__ Cout) {
    gemm_core(A, W, bias, Cout, 3, blockIdx.x * 128, blockIdx.y * 128);
}

// ---------------- flash attention: S^T trick, full-rate PV ----------------
// (unchanged from r2)
__global__ __launch_bounds__(256, 2) void attn_kernel(
    const bf16* __restrict__ Qh, const bf16* __restrict__ Kh,
    const bf16* __restrict__ Vtg, bf16* __restrict__ AO)
{
    __shared__ bf16 Kl[64 * 64];   // [key][d], 16B chunk c holds src chunk c^(key&7)
    __shared__ bf16 Vl[64 * 64];   // [d][key'], 16B chunk c holds src chunk c^(d&7)

    const int tid = threadIdx.x;
    const int lane = tid & 63, wave = tid >> 6;
    const int l15 = lane & 15, quad = lane >> 4, l7 = l15 & 7;
    const int h = blockIdx.y, b = blockIdx.z;
    const size_t base = (size_t)(b * 16 + h) << 17;   // * 2048 * 64
    const int q0 = blockIdx.x * 256 + wave * 64;

    // Q fragments (pre-scaled by QSCALE): B operand of S^T
    bf16x8 qf[4][2];
#pragma unroll
    for (int qt = 0; qt < 4; ++qt)
#pragma unroll
        for (int ks = 0; ks < 2; ++ks)
            qf[qt][ks] = *(const bf16x8*)(Qh + base + (q0 + qt * 16 + l15) * 64 + ks * 32 + quad * 8);

    f32x4 o[4][4] = {};   // O^T tiles: [dt][qt], lane l15=q, rows d=quad*4+r
    float ls[4] = {};     // per-q partial row sums (q = l15)

    const int sr = tid >> 3;
    const int sc0 = ((tid & 7) ^ (sr & 7)) * 8;
    const int sr2 = sr + 32;

    for (int kt = 0; kt < 2048; kt += 64) {
        __syncthreads();
        async_cp16(Kh + base + (size_t)(kt + sr) * 64 + sc0, Kl + tid * 8);
        async_cp16(Kh + base + (size_t)(kt + sr2) * 64 + sc0, Kl + (tid + 256) * 8);
        async_cp16(Vtg + base + (size_t)sr * 2048 + kt + sc0, Vl + tid * 8);
        async_cp16(Vtg + base + (size_t)sr2 * 2048 + kt + sc0, Vl + (tid + 256) * 8);
        __syncthreads();

        bf16x8 kb[2][4];
#pragma unroll
        for (int ks = 0; ks < 2; ++ks)
#pragma unroll
            for (int ktile = 0; ktile < 4; ++ktile)
                kb[ks][ktile] = *(const bf16x8*)(Kl + (ktile * 16 + l15) * 64 + (((ks * 4 + quad) ^ l7) * 8));

        bf16x8 pf[4][2];
#pragma unroll
        for (int qt = 0; qt < 4; ++qt) {
            f32x4 sc[4] = {};
#pragma unroll
            for (int ks = 0; ks < 2; ++ks)
#pragma unroll
                for (int ktile = 0; ktile < 4; ++ktile)
                    sc[ktile] = MFMA16(kb[ks][ktile], qf[qt][ks], sc[ktile]);
            float sum = 0.0f;
#pragma unroll
            for (int kc = 0; kc < 2; ++kc) {
                bf16x8 pk;
#pragma unroll
                for (int t = 0; t < 2; ++t)
#pragma unroll
                    for (int r = 0; r < 4; ++r) {
                        float p = __builtin_amdgcn_exp2f(sc[kc * 2 + t][r]);
                        sum += p;
                        pk[t * 4 + r] = (bf16)p;
                    }
                pf[qt][kc] = pk;
            }
            ls[qt] += sum;
        }

        bf16x8 va[4][2];
#pragma unroll
        for (int dt = 0; dt < 4; ++dt)
#pragma unroll
            for (int kc = 0; kc < 2; ++kc)
                va[dt][kc] = *(const bf16x8*)(Vl + (dt * 16 + l15) * 64 + (((kc * 4 + quad) ^ l7) * 8));

#pragma unroll
        for (int dt = 0; dt < 4; ++dt)
#pragma unroll
            for (int qt = 0; qt < 4; ++qt)
#pragma unroll
                for (int kc = 0; kc < 2; ++kc)
                    o[dt][qt] = MFMA16(va[dt][kc], pf[qt][kc], o[dt][qt]);
    }

#pragma unroll
    for (int qt = 0; qt < 4; ++qt) {
        float l = ls[qt];
        l += __shfl_xor(l, 16, 64);
        l += __shfl_xor(l, 32, 64);
        float inv = 1.0f / l;
        size_t rb = ((size_t)(b * 2048 + q0 + qt * 16 + l15)) * 1024 + h * 64;
#pragma unroll
        for (int dt = 0; dt < 4; ++dt) {
            bf16x4 ov = {(bf16)(o[dt][qt][0] * inv), (bf16)(o[dt][qt][1] * inv),
                         (bf16)(o[dt][qt][2] * inv), (bf16)(o[dt][qt][3] * inv)};
            *(bf16x4*)(AO + rb + dt * 16 + quad * 4) = ov;
        }
    }
}

// ---------------- host ----------------
extern "C" void kernel_launch(void* const* d_in, const int* in_sizes, int n_in,
                              void* d_out, int out_size, void* d_ws, size_t ws_size,
                              hipStream_t stream) {
    const float* q  = (const float*)d_in[0];
    const float* k  = (const float*)d_in[1];
    const float* v  = (const float*)d_in[2];
    const float* Wq = (const float*)d_in[3];
    const float* bq = (const float*)d_in[4];
    const float* Wk = (const float*)d_in[5];
    const float* bk = (const float*)d_in[6];
    const float* Wv = (const float*)d_in[7];
    const float* bv = (const float*)d_in[8];
    const float* Wo = (const float*)d_in[9];
    const float* bo = (const float*)d_in[10];
    float* out = (float*)d_out;

    const size_t NX = (size_t)8192 * 1024;
    const size_t NW = (size_t)1024 * 1024;
    bf16* ws  = (bf16*)d_ws;
    bf16* Xq  = ws;            // reused as AO after projections
    bf16* Xk  = Xq + NX;
    bf16* Xv  = Xk + NX;
    bf16* Wqb = Xv + NX;
    bf16* Wkb = Wqb + NW;
    bf16* Wvb = Wkb + NW;
    bf16* Wob = Wvb + NW;
    bf16* Qh  = Wob + NW;      // [B,H,S,D], pre-scaled by QSCALE
    bf16* Kh  = Qh + NX;       // [B,H,S,D]
    bf16* Vt  = Kh + NX;       // [B,H,D,S'] (tokens permuted within 32-groups)
    bf16* AO  = Xq;

    CvtArgs ca;
    ca.src[0] = q;  ca.dst[0] = Xq;
    ca.src[1] = k;  ca.dst[1] = Xk;
    ca.src[2] = v;  ca.dst[2] = Xv;
    ca.src[3] = Wq; ca.dst[3] = Wqb;
    ca.src[4] = Wk; ca.dst[4] = Wkb;
    ca.src[5] = Wv; ca.dst[5] = Wvb;
    ca.src[6] = Wo; ca.dst[6] = Wob;
    cvt_all<<<14336, 256, 0, stream>>>(ca);

    QkvArgs t;
    t.A[0] = Xq;  t.W[0] = Wqb; t.bias[0] = bq; t.out[0] = Qh;
    t.A[1] = Xk;  t.W[1] = Wkb; t.bias[1] = bk; t.out[1] = Kh;
    t.A[2] = Wvb; t.W[2] = Xv;  t.bias[2] = bv; t.out[2] = Vt;   // V^T: A=Wv, W=Xv
    qkv_gemm<<<384, 512, 0, stream>>>(t);

    attn_kernel<<<dim3(8, 16, 4), dim3(256, 1, 1), 0, stream>>>(Qh, Kh, Vt, AO);

    oproj_gemm<<<dim3(64, 8), dim3(256, 1, 1), 0, stream>>>(AO, Wob, bo, out);
}

// Round 5
// 337.553 us; speedup vs baseline: 1.0824x; 1.0498x over previous
//
#include <hip/hip_runtime.h>

typedef __bf16 bf16;
typedef __bf16 bf16x4 __attribute__((ext_vector_type(4)));
typedef __bf16 bf16x8 __attribute__((ext_vector_type(8)));
typedef float f32x4 __attribute__((ext_vector_type(4)));

#define MFMA16(a, b, c) __builtin_amdgcn_mfma_f32_16x16x32_bf16((a), (b), (c), 0, 0, 0)

// Q pre-scale: 1/sqrt(64) * log2(e), so attention uses exp2 directly.
#define QSCALE 0.1803368808f

__device__ __forceinline__ void async_cp16(const bf16* g, bf16* l) {
    __builtin_amdgcn_global_load_lds((const __attribute__((address_space(1))) void*)g,
                                     (__attribute__((address_space(3))) void*)l, 16, 0, 0);
}

// ---------------- fused fp32 -> bf16 conversion (one launch, 7 tensors) ----
struct CvtArgs { const float* src[7]; bf16* dst[7]; };
__global__ void cvt_all(CvtArgs a) {
    int bx = blockIdx.x, t, off;
    if (bx < 12288) { t = bx >> 12;            off = bx & 4095; }
    else            { t = 3 + ((bx - 12288) >> 9); off = (bx - 12288) & 511; }
    size_t i = (size_t)off * 256 + threadIdx.x;
    const float4* p = (const float4*)(a.src[t] + i * 8);
    float4 x = p[0], y = p[1];
    bf16x8 o;
    o[0] = (bf16)x.x; o[1] = (bf16)x.y; o[2] = (bf16)x.z; o[3] = (bf16)x.w;
    o[4] = (bf16)y.x; o[5] = (bf16)y.y; o[6] = (bf16)y.z; o[7] = (bf16)y.w;
    *(bf16x8*)(a.dst[t] + i * 8) = o;
}

// ---------------- 128x128 GEMM core (r2-proven: 96.5us qkv, 0 conflicts) --
// BK=64, single-buffered. Row = 128B = 8 chunks; both-sides swizzle c^(r&7):
// global source chunk pre-swizzled, LDS linear, read XORs chunk with row&7.
// mode 0: Q -> bf16 [B,H,S,D], val=(acc+bias[col])*QSCALE
// mode 1: K -> bf16 [B,H,S,D]
// mode 2: V^T -> bf16 [B,H,D,S'], tokens permuted within 32-groups
// mode 3: fp32 row-major [M,1024], bias[col]
__device__ __forceinline__ void gemm_core(
    const bf16* __restrict__ A, const bf16* __restrict__ W,
    const float* __restrict__ bias, void* __restrict__ Cout,
    int mode, int m0, int n0)
{
    __shared__ bf16 As[128 * 64];
    __shared__ bf16 Bs[128 * 64];
    const int K = 1024;
    const int tid = threadIdx.x;
    const int lane = tid & 63, wave = tid >> 6;
    const int l15 = lane & 15, quad = lane >> 4, l7 = l15 & 7;
    const int wm = wave >> 1, wn = wave & 1;

    f32x4 acc[4][4] = {};

    const int rb = tid >> 3;
    const int cg8 = ((tid & 7) ^ (rb & 7)) * 8;
    const bf16* Ag = A + (size_t)(m0 + rb) * K + cg8;
    const bf16* Wg = W + (size_t)(n0 + rb) * K + cg8;
    bf16* Al = As + tid * 8;
    bf16* Bl = Bs + tid * 8;

    for (int k0 = 0; k0 < K; k0 += 64) {
        __syncthreads();
#pragma unroll
        for (int j = 0; j < 4; ++j) {
            async_cp16(Ag + k0 + (size_t)(j * 32) * K, Al + j * 2048);
            async_cp16(Wg + k0 + (size_t)(j * 32) * K, Bl + j * 2048);
        }
        __syncthreads();

#pragma unroll
        for (int ks = 0; ks < 2; ++ks) {
            bf16x8 af[4], bfr[4];
#pragma unroll
            for (int t = 0; t < 4; ++t) {
                const int sw = ((ks * 4 + quad) ^ l7) * 8;
                af[t]  = *(const bf16x8*)(As + (wm * 64 + t * 16 + l15) * 64 + sw);
                bfr[t] = *(const bf16x8*)(Bs + (wn * 64 + t * 16 + l15) * 64 + sw);
            }
#pragma unroll
            for (int mt = 0; mt < 4; ++mt)
#pragma unroll
                for (int nt = 0; nt < 4; ++nt)
                    acc[mt][nt] = MFMA16(af[mt], bfr[nt], acc[mt][nt]);
        }
    }

#pragma unroll
    for (int mt = 0; mt < 4; ++mt) {
#pragma unroll
        for (int nt = 0; nt < 4; ++nt) {
            int col = n0 + wn * 64 + nt * 16 + l15;
            float bcol = (mode == 2) ? 0.0f : bias[col];
#pragma unroll
            for (int r = 0; r < 4; ++r) {
                int row = m0 + wm * 64 + mt * 16 + quad * 4 + r;
                float val = acc[mt][nt][r];
                if (mode == 2) {
                    val += bias[row];
                    int bb = col >> 11, s = col & 2047;
                    int u = s & 31;
                    int sp = (s & ~31) | (((u >> 2) & 3) * 8 + (u >> 4) * 4 + (u & 3));
                    ((bf16*)Cout)[((size_t)(bb * 1024 + row) << 11) + sp] = (bf16)val;
                } else if (mode == 3) {
                    ((float*)Cout)[(size_t)row * 1024 + col] = val + bcol;
                } else {
                    val += bcol;
                    if (mode == 0) val *= QSCALE;
                    int bb = row >> 11, s = row & 2047, hh = col >> 6, d = col & 63;
                    ((bf16*)Cout)[(((size_t)(bb * 16 + hh) * 2048 + s) << 6) + d] = (bf16)val;
                }
            }
        }
    }
}

struct QkvArgs {
    const bf16* A[3];
    const bf16* W[3];
    const float* bias[3];
    bf16* out[3];
};

// grid (512, 3). XCD/L2-aware remap (T1): the 8 blocks sharing an A-row-panel
// (z<2) or an Xv-col-panel (z=2) get CONSECUTIVE per-XCD slots on ONE XCD
// (hw xcd ~ linear_bid % 8; stride-8 bids share an XCD and are temporally
// adjacent there). Working set/XCD = one 256KB panel + 2MB W < 4MB L2.
//   lo=bid&7 (xcd), mid=(bid>>3)&7, hi=bid>>6
//   z<2: m_idx = lo + hi*8 (64 panels), n_idx = mid (8)
//   z=2: n_idx = lo + hi*8 (64 panels), m_idx = mid (8)
__global__ __launch_bounds__(256) void qkv_gemm(QkvArgs t) {
    int z = blockIdx.y;
    int bid = blockIdx.x;
    int lo = bid & 7, mid = (bid >> 3) & 7, hi = bid >> 6;
    int m0, n0;
    if (z < 2) { m0 = (lo + hi * 8) * 128; n0 = mid * 128; }
    else       { m0 = mid * 128;           n0 = (lo + hi * 8) * 128; }
    gemm_core(t.A[z], t.W[z], t.bias[z], t.out[z], z, m0, n0);
}

// O-projection: fp32 out, 128^2 core
__global__ __launch_bounds__(256) void oproj_gemm(
    const bf16* __restrict__ A, const bf16* __restrict__ W,
    const float* __restrict__ bias, float* __restrict__ Cout) {
    gemm_core(A, W, bias, Cout, 3, blockIdx.x * 128, blockIdx.y * 128);
}

// ---------------- flash attention: S^T trick, full-rate PV ----------------
// 1D grid 512: g = bid&63 (head-group, fixes XCD residue), qi = bid>>6.
// All 8 q-tiles of one (b,h) land on ONE XCD; per-XCD K/V = 8 groups x 512KB
// = 4MB = L2 -> K/V stage loads become L2 hits instead of L3/HBM.
// S^T = K.Q^T (A=K-frag, B=Q-frag); V^T token-permuted to match PV B-operand.
__global__ __launch_bounds__(256, 2) void attn_kernel(
    const bf16* __restrict__ Qh, const bf16* __restrict__ Kh,
    const bf16* __restrict__ Vtg, bf16* __restrict__ AO)
{
    __shared__ bf16 Kl[64 * 64];   // [key][d], 16B chunk c holds src chunk c^(key&7)
    __shared__ bf16 Vl[64 * 64];   // [d][key'], 16B chunk c holds src chunk c^(d&7)

    const int tid = threadIdx.x;
    const int lane = tid & 63, wave = tid >> 6;
    const int l15 = lane & 15, quad = lane >> 4, l7 = l15 & 7;
    const int g = blockIdx.x & 63, qi = blockIdx.x >> 6;
    const int h = g & 15, b = g >> 4;
    const size_t base = (size_t)(b * 16 + h) << 17;   // * 2048 * 64
    const int q0 = qi * 256 + wave * 64;

    // Q fragments (pre-scaled by QSCALE): B operand of S^T
    bf16x8 qf[4][2];
#pragma unroll
    for (int qt = 0; qt < 4; ++qt)
#pragma unroll
        for (int ks = 0; ks < 2; ++ks)
            qf[qt][ks] = *(const bf16x8*)(Qh + base + (q0 + qt * 16 + l15) * 64 + ks * 32 + quad * 8);

    f32x4 o[4][4] = {};   // O^T tiles: [dt][qt], lane l15=q, rows d=quad*4+r
    float ls[4] = {};     // per-q partial row sums (q = l15)

    const int sr = tid >> 3;
    const int sc0 = ((tid & 7) ^ (sr & 7)) * 8;
    const int sr2 = sr + 32;

    for (int kt = 0; kt < 2048; kt += 64) {
        __syncthreads();
        async_cp16(Kh + base + (size_t)(kt + sr) * 64 + sc0, Kl + tid * 8);
        async_cp16(Kh + base + (size_t)(kt + sr2) * 64 + sc0, Kl + (tid + 256) * 8);
        async_cp16(Vtg + base + (size_t)sr * 2048 + kt + sc0, Vl + tid * 8);
        async_cp16(Vtg + base + (size_t)sr2 * 2048 + kt + sc0, Vl + (tid + 256) * 8);
        __syncthreads();

        bf16x8 kb[2][4];
#pragma unroll
        for (int ks = 0; ks < 2; ++ks)
#pragma unroll
            for (int ktile = 0; ktile < 4; ++ktile)
                kb[ks][ktile] = *(const bf16x8*)(Kl + (ktile * 16 + l15) * 64 + (((ks * 4 + quad) ^ l7) * 8));

        bf16x8 pf[4][2];
#pragma unroll
        for (int qt = 0; qt < 4; ++qt) {
            f32x4 sc[4] = {};
#pragma unroll
            for (int ks = 0; ks < 2; ++ks)
#pragma unroll
                for (int ktile = 0; ktile < 4; ++ktile)
                    sc[ktile] = MFMA16(kb[ks][ktile], qf[qt][ks], sc[ktile]);
            float sum = 0.0f;
#pragma unroll
            for (int kc = 0; kc < 2; ++kc) {
                bf16x8 pk;
#pragma unroll
                for (int t = 0; t < 2; ++t)
#pragma unroll
                    for (int r = 0; r < 4; ++r) {
                        float p = __builtin_amdgcn_exp2f(sc[kc * 2 + t][r]);
                        sum += p;
                        pk[t * 4 + r] = (bf16)p;
                    }
                pf[qt][kc] = pk;
            }
            ls[qt] += sum;
        }

        bf16x8 va[4][2];
#pragma unroll
        for (int dt = 0; dt < 4; ++dt)
#pragma unroll
            for (int kc = 0; kc < 2; ++kc)
                va[dt][kc] = *(const bf16x8*)(Vl + (dt * 16 + l15) * 64 + (((kc * 4 + quad) ^ l7) * 8));

#pragma unroll
        for (int dt = 0; dt < 4; ++dt)
#pragma unroll
            for (int qt = 0; qt < 4; ++qt)
#pragma unroll
                for (int kc = 0; kc < 2; ++kc)
                    o[dt][qt] = MFMA16(va[dt][kc], pf[qt][kc], o[dt][qt]);
    }

#pragma unroll
    for (int qt = 0; qt < 4; ++qt) {
        float l = ls[qt];
        l += __shfl_xor(l, 16, 64);
        l += __shfl_xor(l, 32, 64);
        float inv = 1.0f / l;
        size_t rb = ((size_t)(b * 2048 + q0 + qt * 16 + l15)) * 1024 + h * 64;
#pragma unroll
        for (int dt = 0; dt < 4; ++dt) {
            bf16x4 ov = {(bf16)(o[dt][qt][0] * inv), (bf16)(o[dt][qt][1] * inv),
                         (bf16)(o[dt][qt][2] * inv), (bf16)(o[dt][qt][3] * inv)};
            *(bf16x4*)(AO + rb + dt * 16 + quad * 4) = ov;
        }
    }
}

// ---------------- host ----------------
extern "C" void kernel_launch(void* const* d_in, const int* in_sizes, int n_in,
                              void* d_out, int out_size, void* d_ws, size_t ws_size,
                              hipStream_t stream) {
    const float* q  = (const float*)d_in[0];
    const float* k  = (const float*)d_in[1];
    const float* v  = (const float*)d_in[2];
    const float* Wq = (const float*)d_in[3];
    const float* bq = (const float*)d_in[4];
    const float* Wk = (const float*)d_in[5];
    const float* bk = (const float*)d_in[6];
    const float* Wv = (const float*)d_in[7];
    const float* bv = (const float*)d_in[8];
    const float* Wo = (const float*)d_in[9];
    const float* bo = (const float*)d_in[10];
    float* out = (float*)d_out;

    const size_t NX = (size_t)8192 * 1024;
    const size_t NW = (size_t)1024 * 1024;
    bf16* ws  = (bf16*)d_ws;
    bf16* Xq  = ws;            // reused as AO after projections
    bf16* Xk  = Xq + NX;
    bf16* Xv  = Xk + NX;
    bf16* Wqb = Xv + NX;
    bf16* Wkb = Wqb + NW;
    bf16* Wvb = Wkb + NW;
    bf16* Wob = Wvb + NW;
    bf16* Qh  = Wob + NW;      // [B,H,S,D], pre-scaled by QSCALE
    bf16* Kh  = Qh + NX;       // [B,H,S,D]
    bf16* Vt  = Kh + NX;       // [B,H,D,S'] (tokens permuted within 32-groups)
    bf16* AO  = Xq;

    CvtArgs ca;
    ca.src[0] = q;  ca.dst[0] = Xq;
    ca.src[1] = k;  ca.dst[1] = Xk;
    ca.src[2] = v;  ca.dst[2] = Xv;
    ca.src[3] = Wq; ca.dst[3] = Wqb;
    ca.src[4] = Wk; ca.dst[4] = Wkb;
    ca.src[5] = Wv; ca.dst[5] = Wvb;
    ca.src[6] = Wo; ca.dst[6] = Wob;
    cvt_all<<<14336, 256, 0, stream>>>(ca);

    QkvArgs t;
    t.A[0] = Xq;  t.W[0] = Wqb; t.bias[0] = bq; t.out[0] = Qh;
    t.A[1] = Xk;  t.W[1] = Wkb; t.bias[1] = bk; t.out[1] = Kh;
    t.A[2] = Wvb; t.W[2] = Xv;  t.bias[2] = bv; t.out[2] = Vt;   // V^T: A=Wv, W=Xv
    qkv_gemm<<<dim3(512, 3), dim3(256, 1, 1), 0, stream>>>(t);

    attn_kernel<<<512, 256, 0, stream>>>(Qh, Kh, Vt, AO);

    oproj_gemm<<<dim3(64, 8), dim3(256, 1, 1), 0, stream>>>(AO, Wob, bo, out);
}